// Round 1
// baseline (438.368 us; speedup 1.0000x reference)
//
#include <hip/hip_runtime.h>
#include <stdint.h>

// ---------------------------------------------------------------------------
// Speaker pairwise loss.  Two fused bf16-MFMA GEMM passes over sim = F·F^T:
//   pass1: per-row min(pos sims), max(neg sims)  (ordered-uint atomic min/max)
//   pass2: per-row masked exp sums with dynamic thresholds from pass1
//   finalize: loss = sum(valid ? rowloss : 0)/B, prec1 = 1 - mean(valid)
// ws layout: minord[B] u32 | maxord[B] u32 | psum[B] f32 | nsum[B] f32  (128KB)
// ---------------------------------------------------------------------------

typedef __attribute__((ext_vector_type(8))) short short8;   // 8 bf16 (4 VGPRs)
typedef __attribute__((ext_vector_type(4))) float floatx4;  // MFMA C/D

constexpr int D = 256;     // feature dim (full K staged per 64-chunk)
constexpr int BM = 128;
constexpr int BN = 128;
constexpr int BK = 64;
constexpr int LDT = BK + 8;      // 72 shorts = 144B row stride: 16B-aligned, 4-bank shift/row
constexpr int CTILES = 8;        // column tiles per block => each block does 128 x 1024

constexpr unsigned ORD_POS_INF = 0xFF800000u;  // ford(+inf)
constexpr unsigned ORD_NEG_INF = 0x007FFFFFu;  // ford(-inf)

__device__ __forceinline__ unsigned ford(float f) {
  unsigned u = __float_as_uint(f);
  return (u & 0x80000000u) ? ~u : (u | 0x80000000u);
}
__device__ __forceinline__ float fdec(unsigned x) {
  unsigned u = (x & 0x80000000u) ? (x ^ 0x80000000u) : ~x;
  return __uint_as_float(u);
}
__device__ __forceinline__ unsigned f2bf(float f) {  // fp32 -> bf16 bits, RNE
  unsigned u = __float_as_uint(f);
  return (u + 0x7FFFu + ((u >> 16) & 1u)) >> 16;
}

__global__ void init_kernel(unsigned* __restrict__ minord, unsigned* __restrict__ maxord,
                            float* __restrict__ psum, float* __restrict__ nsum, int Bn) {
  int i = blockIdx.x * blockDim.x + threadIdx.x;
  if (i < Bn) {
    minord[i] = ORD_POS_INF;
    maxord[i] = ORD_NEG_INF;
    psum[i] = 0.f;
    nsum[i] = 0.f;
  }
}

template <int PASS>
__global__ __launch_bounds__(256, 2)
void pair_kernel(const float* __restrict__ feats, const int* __restrict__ labels,
                 unsigned* __restrict__ minord, unsigned* __restrict__ maxord,
                 float* __restrict__ psum, float* __restrict__ nsum) {
  __shared__ short As[BM * LDT];   // 18KB
  __shared__ short Bs[BN * LDT];   // 18KB
  __shared__ int   labA[BM];
  __shared__ int   labB[BN];
  __shared__ float tmnS[BM];       // pass2: min_pos - margin
  __shared__ float tmxS[BM];       // pass2: max_neg + margin

  const int tid  = threadIdx.x;
  const int lane = tid & 63;
  const int wave = tid >> 6;
  const int l15  = lane & 15;
  const int quad = lane >> 4;
  const int wr   = (wave >> 1) * 64;   // wave row offset in tile
  const int wc   = (wave & 1) * 64;    // wave col offset in tile

  const int row0    = blockIdx.x * BM;
  const int colbase = blockIdx.y * (BN * CTILES);

  const float ONE_EPS = 1.0f - 1e-5f;

  if (tid < BM) {
    int r = row0 + tid;
    labA[tid] = labels[r];
    if (PASS == 2) {
      tmnS[tid] = fdec(minord[r]) - 0.1f;   // inf-safe
      tmxS[tid] = fdec(maxord[r]) + 0.1f;
    }
  }

  float mnv[16], mxv[16], psv[16], nsv[16];
#pragma unroll
  for (int i = 0; i < 16; ++i) {
    mnv[i] = __builtin_inff();
    mxv[i] = -__builtin_inff();
    psv[i] = 0.f;
    nsv[i] = 0.f;
  }

  for (int ct = 0; ct < CTILES; ++ct) {
    const int col0 = colbase + ct * BN;
    __syncthreads();                       // protect labB vs prior epilogue readers
    if (tid < BN) labB[tid] = labels[col0 + tid];

    floatx4 acc[4][4];
#pragma unroll
    for (int rf = 0; rf < 4; ++rf)
#pragma unroll
      for (int cf = 0; cf < 4; ++cf)
        acc[rf][cf] = (floatx4)(0.f);

    for (int kc = 0; kc < D; kc += BK) {
      // ---- stage A and B chunks: fp32 global -> bf16 LDS (coalesced float4) ----
#pragma unroll
      for (int i = 0; i < 8; ++i) {
        int idx = i * 256 + tid;           // 0..2047 float4 slots
        int row = idx >> 4;                // 0..127
        int c4  = idx & 15;                // 0..15
        float4 v = *(const float4*)(feats + (size_t)(row0 + row) * D + kc + c4 * 4);
        unsigned lo = f2bf(v.x) | (f2bf(v.y) << 16);
        unsigned hi = f2bf(v.z) | (f2bf(v.w) << 16);
        *(uint2*)(As + row * LDT + c4 * 4) = make_uint2(lo, hi);
        float4 w = *(const float4*)(feats + (size_t)(col0 + row) * D + kc + c4 * 4);
        lo = f2bf(w.x) | (f2bf(w.y) << 16);
        hi = f2bf(w.z) | (f2bf(w.w) << 16);
        *(uint2*)(Bs + row * LDT + c4 * 4) = make_uint2(lo, hi);
      }
      __syncthreads();
      // ---- MFMA over this K chunk ----
#pragma unroll
      for (int ks = 0; ks < 2; ++ks) {
        const int kb = ks * 32;
        short8 a[4], b[4];
#pragma unroll
        for (int rf = 0; rf < 4; ++rf)
          a[rf] = *(const short8*)(As + (wr + rf * 16 + l15) * LDT + kb + quad * 8);
#pragma unroll
        for (int cf = 0; cf < 4; ++cf)
          b[cf] = *(const short8*)(Bs + (wc + cf * 16 + l15) * LDT + kb + quad * 8);
#pragma unroll
        for (int rf = 0; rf < 4; ++rf)
#pragma unroll
          for (int cf = 0; cf < 4; ++cf)
            acc[rf][cf] = __builtin_amdgcn_mfma_f32_16x16x32_bf16(a[rf], b[cf], acc[rf][cf], 0, 0, 0);
      }
      __syncthreads();
    }

    // ---- epilogue for this 128x128 tile ----
    int labc[4];
#pragma unroll
    for (int cf = 0; cf < 4; ++cf) labc[cf] = labB[wc + cf * 16 + l15];

#pragma unroll
    for (int rf = 0; rf < 4; ++rf) {
#pragma unroll
      for (int r = 0; r < 4; ++r) {
        const int ri = wr + rf * 16 + quad * 4 + r;   // C/D layout: row = quad*4 + reg
        const int lr = labA[ri];
        float tmn = 0.f, tmx = 0.f;
        if (PASS == 2) { tmn = tmnS[ri]; tmx = tmxS[ri]; }
#pragma unroll
        for (int cf = 0; cf < 4; ++cf) {
          float sim = acc[rf][cf][r];
          bool same = (lr == labc[cf]);
          if (PASS == 1) {
            if (same) {
              if (sim < ONE_EPS) mnv[rf * 4 + r] = fminf(mnv[rf * 4 + r], sim);
            } else {
              mxv[rf * 4 + r] = fmaxf(mxv[rf * 4 + r], sim);
            }
          } else {
            if (same) {
              if (sim < ONE_EPS && sim < tmx)
                psv[rf * 4 + r] += __expf(fmaf(-2.f, sim, 1.f));      // exp(-2(sim-.5))
            } else if (sim > tmn) {
              nsv[rf * 4 + r] += 1e-30f;                              // keep any(neg_sel)
              if (sim > 0.22f)                                        // dropped mass < 7e-3
                nsv[rf * 4 + r] += __expf(fmaf(50.f, sim, -25.f));    // exp(50(sim-.5))
            }
          }
        }
      }
    }
  }

  // ---- block-end reduction: combine 16 column-lanes per row, one atomic/row ----
#pragma unroll
  for (int rf = 0; rf < 4; ++rf) {
#pragma unroll
    for (int r = 0; r < 4; ++r) {
      const int grow = row0 + wr + rf * 16 + quad * 4 + r;
      if (PASS == 1) {
        float v = mnv[rf * 4 + r];
        float w = mxv[rf * 4 + r];
#pragma unroll
        for (int m = 1; m < 16; m <<= 1) {
          v = fminf(v, __shfl_xor(v, m));
          w = fmaxf(w, __shfl_xor(w, m));
        }
        if (l15 == 0) {
          atomicMin(minord + grow, ford(v));
          atomicMax(maxord + grow, ford(w));
        }
      } else {
        float p = psv[rf * 4 + r];
        float n = nsv[rf * 4 + r];
#pragma unroll
        for (int m = 1; m < 16; m <<= 1) {
          p += __shfl_xor(p, m);
          n += __shfl_xor(n, m);
        }
        if (l15 == 0) {
          atomicAdd(psum + grow, p);
          atomicAdd(nsum + grow, n);
        }
      }
    }
  }
}

__global__ void finalize_kernel(const float* __restrict__ psum, const float* __restrict__ nsum,
                                float* __restrict__ out, int Bn) {
  __shared__ float sl[4], sc[4];
  float loss = 0.f, cnt = 0.f;
  for (int i = threadIdx.x; i < Bn; i += 256) {
    float p = psum[i], n = nsum[i];
    if (p > 0.f && n > 0.f) {
      loss += 0.5f * log1pf(p) + 0.02f * log1pf(n);
      cnt += 1.f;
    }
  }
#pragma unroll
  for (int m = 1; m < 64; m <<= 1) {
    loss += __shfl_xor(loss, m);
    cnt  += __shfl_xor(cnt, m);
  }
  int wave = threadIdx.x >> 6, lane = threadIdx.x & 63;
  if (lane == 0) { sl[wave] = loss; sc[wave] = cnt; }
  __syncthreads();
  if (threadIdx.x == 0) {
    float L = sl[0] + sl[1] + sl[2] + sl[3];
    float C = sc[0] + sc[1] + sc[2] + sc[3];
    out[0] = L / (float)Bn;
    out[1] = 1.0f - C / (float)Bn;
  }
}

extern "C" void kernel_launch(void* const* d_in, const int* in_sizes, int n_in,
                              void* d_out, int out_size, void* d_ws, size_t ws_size,
                              hipStream_t stream) {
  const float* feats  = (const float*)d_in[0];
  const int*   labels = (const int*)d_in[1];
  const int Bn = in_sizes[1];          // 8192
  float* out = (float*)d_out;

  unsigned* minord = (unsigned*)d_ws;
  unsigned* maxord = minord + Bn;
  float*    psum   = (float*)(maxord + Bn);
  float*    nsum   = psum + Bn;

  init_kernel<<<(Bn + 255) / 256, 256, 0, stream>>>(minord, maxord, psum, nsum, Bn);

  dim3 grid(Bn / BM, Bn / (BN * CTILES));   // 64 x 8 = 512 blocks
  pair_kernel<1><<<grid, 256, 0, stream>>>(feats, labels, minord, maxord, psum, nsum);
  pair_kernel<2><<<grid, 256, 0, stream>>>(feats, labels, minord, maxord, psum, nsum);
  finalize_kernel<<<1, 256, 0, stream>>>(psum, nsum, out, Bn);
}

// Round 2
// 216.917 us; speedup vs baseline: 2.0209x; 2.0209x over previous
//
#include <hip/hip_runtime.h>
#include <stdint.h>

// ---------------------------------------------------------------------------
// Speaker pairwise loss.  Two fused bf16-MFMA GEMM passes over sim = F·F^T.
//   convert: fp32 feats -> bf16 once (ws)
//   pass1: per-row min(pos sims), max(neg sims)  (ordered-uint atomic min/max)
//   pass2: per-row masked exp sums with dynamic thresholds from pass1
//   finalize: loss, prec1
// Staging: global_load_lds width=16 from bf16 buffer, XOR-swizzled (no pad).
// ws: minord[B] u32 | maxord[B] u32 | psum[B] f32 | nsum[B] f32 | featsbf16[B*D]
// ---------------------------------------------------------------------------

typedef __attribute__((ext_vector_type(8))) short short8;   // 8 bf16 (4 VGPRs)
typedef __attribute__((ext_vector_type(4))) float floatx4;  // MFMA C/D

constexpr int D = 256;
constexpr int BM = 128;
constexpr int BN = 128;
constexpr int BK = 64;
constexpr int CTILES = 8;        // each block covers 128 x 1024 of sim

constexpr unsigned ORD_POS_INF = 0xFF800000u;  // ford(+inf)
constexpr unsigned ORD_NEG_INF = 0x007FFFFFu;  // ford(-inf)

__device__ __forceinline__ unsigned ford(float f) {
  unsigned u = __float_as_uint(f);
  return (u & 0x80000000u) ? ~u : (u | 0x80000000u);
}
__device__ __forceinline__ float fdec(unsigned x) {
  unsigned u = (x & 0x80000000u) ? (x ^ 0x80000000u) : ~x;
  return __uint_as_float(u);
}
__device__ __forceinline__ unsigned f2bf(float f) {  // fp32 -> bf16 bits, RNE
  unsigned u = __float_as_uint(f);
  return (u + 0x7FFFu + ((u >> 16) & 1u)) >> 16;
}

// async 16B global->LDS (lane i lands at ldsbase + i*16; gather addr per lane)
__device__ __forceinline__ void gl_lds16(const void* g, void* l) {
  __builtin_amdgcn_global_load_lds(
      (const __attribute__((address_space(1))) unsigned int*)g,
      (__attribute__((address_space(3))) unsigned int*)l, 16, 0, 0);
}

__global__ void init_kernel(unsigned* __restrict__ minord, unsigned* __restrict__ maxord,
                            float* __restrict__ psum, float* __restrict__ nsum, int Bn) {
  int i = blockIdx.x * blockDim.x + threadIdx.x;
  if (i < Bn) {
    minord[i] = ORD_POS_INF;
    maxord[i] = ORD_NEG_INF;
    psum[i] = 0.f;
    nsum[i] = 0.f;
  }
}

__global__ void convert_kernel(const float* __restrict__ feats,
                               unsigned short* __restrict__ fb, int n4) {
  int i = blockIdx.x * blockDim.x + threadIdx.x;   // one float4 -> 4 bf16
  if (i < n4) {
    float4 v = ((const float4*)feats)[i];
    unsigned lo = f2bf(v.x) | (f2bf(v.y) << 16);
    unsigned hi = f2bf(v.z) | (f2bf(v.w) << 16);
    ((uint2*)fb)[i] = make_uint2(lo, hi);
  }
}

template <int PASS>
__global__ __launch_bounds__(256)
void pair_kernel(const unsigned short* __restrict__ fb, const int* __restrict__ labels,
                 unsigned* __restrict__ minord, unsigned* __restrict__ maxord,
                 float* __restrict__ psum, float* __restrict__ nsum) {
  // unpadded (global_load_lds requires lane-contiguous LDS); XOR swizzle kills conflicts
  __shared__ short As[BM * BK];   // 16KB: row stride 64 shorts (128B)
  __shared__ short Bs[BN * BK];   // 16KB
  __shared__ int   labA[BM];
  __shared__ int   labB[BN];
  __shared__ float tmnS[BM];      // pass2: min_pos - margin
  __shared__ float tmxS[BM];      // pass2: max_neg + margin

  const int tid  = threadIdx.x;
  const int lane = tid & 63;
  const int wave = tid >> 6;
  const int l15  = lane & 15;
  const int quad = lane >> 4;
  const int wr   = (wave >> 1) * 64;
  const int wc   = (wave & 1) * 64;

  const int row0    = blockIdx.x * BM;
  const int colbase = blockIdx.y * (BN * CTILES);

  const float ONE_EPS = 1.0f - 1e-5f;

  if (tid < BM) {
    int r = row0 + tid;
    labA[tid] = labels[r];
    if (PASS == 2) {
      tmnS[tid] = fdec(minord[r]) - 0.1f;
      tmxS[tid] = fdec(maxord[r]) + 0.1f;
    }
  }

  // staging geometry: wave covers 32 rows (4 issues x 8 rows), lane -> (rowoff, slot)
  const int srow = (wave << 5) + (lane >> 3);  // +8 per issue
  const int slot = lane & 7;                   // 16B group within 128B row chunk

  // fragment rows (fixed per lane)
  int arow[4], brow[4];
#pragma unroll
  for (int i = 0; i < 4; ++i) {
    arow[i] = wr + i * 16 + l15;
    brow[i] = wc + i * 16 + l15;
  }

  float s0[16], s1[16];   // pass1: min/max; pass2: psum/nsum
#pragma unroll
  for (int i = 0; i < 16; ++i) {
    s0[i] = (PASS == 1) ? __builtin_inff() : 0.f;
    s1[i] = (PASS == 1) ? -__builtin_inff() : 0.f;
  }

  for (int ct = 0; ct < CTILES; ++ct) {
    const int col0 = colbase + ct * BN;
    __syncthreads();                        // protect labB rewrite vs prior epilogue
    if (tid < BN) labB[tid] = labels[col0 + tid];

    floatx4 acc[4][4];
#pragma unroll
    for (int rf = 0; rf < 4; ++rf)
#pragma unroll
      for (int cf = 0; cf < 4; ++cf)
        acc[rf][cf] = (floatx4)(0.f);

    for (int kc = 0; kc < 4; ++kc) {
      // ---- async stage A,B 128x64 bf16 chunks, XOR-swizzled on global side ----
#pragma unroll
      for (int j = 0; j < 4; ++j) {
        int r = srow + 8 * j;
        int sw = (slot ^ (r & 7)) << 4;     // swizzled 16B group (bytes)
        const char* ga = (const char*)fb + (((size_t)(row0 + r)) << 9) + (kc << 7) + sw;
        gl_lds16(ga, (char*)As + (r << 7) + (slot << 4));
        const char* gb = (const char*)fb + (((size_t)(col0 + r)) << 9) + (kc << 7) + sw;
        gl_lds16(gb, (char*)Bs + (r << 7) + (slot << 4));
      }
      __syncthreads();
      // ---- MFMA over this K chunk ----
#pragma unroll
      for (int ks = 0; ks < 2; ++ks) {
        const int g = ks * 4 + quad;        // 16B group index within 64-short row
        short8 a[4], b[4];
#pragma unroll
        for (int rf = 0; rf < 4; ++rf)
          a[rf] = *(const short8*)(As + arow[rf] * 64 + ((g ^ (arow[rf] & 7)) << 3));
#pragma unroll
        for (int cf = 0; cf < 4; ++cf)
          b[cf] = *(const short8*)(Bs + brow[cf] * 64 + ((g ^ (brow[cf] & 7)) << 3));
#pragma unroll
        for (int rf = 0; rf < 4; ++rf)
#pragma unroll
          for (int cf = 0; cf < 4; ++cf)
            acc[rf][cf] = __builtin_amdgcn_mfma_f32_16x16x32_bf16(a[rf], b[cf], acc[rf][cf], 0, 0, 0);
      }
      __syncthreads();
    }

    // ---- epilogue for this 128x128 tile ----
    int labc[4];
#pragma unroll
    for (int cf = 0; cf < 4; ++cf) labc[cf] = labB[wc + cf * 16 + l15];

#pragma unroll
    for (int rf = 0; rf < 4; ++rf) {
#pragma unroll
      for (int r = 0; r < 4; ++r) {
        const int ri = wr + rf * 16 + quad * 4 + r;   // C/D layout: row = quad*4 + reg
        const int lr = labA[ri];
        float tmn = 0.f, tmx = 0.f;
        if (PASS == 2) { tmn = tmnS[ri]; tmx = tmxS[ri]; }
#pragma unroll
        for (int cf = 0; cf < 4; ++cf) {
          float sim = acc[rf][cf][r];
          bool same = (lr == labc[cf]);
          if (PASS == 1) {
            if (same) {
              if (sim < ONE_EPS) s0[rf * 4 + r] = fminf(s0[rf * 4 + r], sim);
            } else {
              s1[rf * 4 + r] = fmaxf(s1[rf * 4 + r], sim);
            }
          } else {
            if (same) {
              if (sim < ONE_EPS && sim < tmx)
                s0[rf * 4 + r] += __expf(fmaf(-2.f, sim, 1.f));      // exp(-2(sim-.5))
            } else if (sim > tmn) {
              s1[rf * 4 + r] += 1e-30f;                              // keep any(neg_sel)
              if (sim > 0.22f)                                       // dropped mass < 7e-3
                s1[rf * 4 + r] += __expf(fmaf(50.f, sim, -25.f));    // exp(50(sim-.5))
            }
          }
        }
      }
    }
  }

  // ---- block-end: combine 16 column-lanes per row, one atomic/row ----
#pragma unroll
  for (int rf = 0; rf < 4; ++rf) {
#pragma unroll
    for (int r = 0; r < 4; ++r) {
      const int grow = row0 + wr + rf * 16 + quad * 4 + r;
      float v = s0[rf * 4 + r];
      float w = s1[rf * 4 + r];
      if (PASS == 1) {
#pragma unroll
        for (int m = 1; m < 16; m <<= 1) {
          v = fminf(v, __shfl_xor(v, m));
          w = fmaxf(w, __shfl_xor(w, m));
        }
        if (l15 == 0) {
          atomicMin(minord + grow, ford(v));
          atomicMax(maxord + grow, ford(w));
        }
      } else {
#pragma unroll
        for (int m = 1; m < 16; m <<= 1) {
          v += __shfl_xor(v, m);
          w += __shfl_xor(w, m);
        }
        if (l15 == 0) {
          atomicAdd(psum + grow, v);
          atomicAdd(nsum + grow, w);
        }
      }
    }
  }
}

__global__ void finalize_kernel(const float* __restrict__ psum, const float* __restrict__ nsum,
                                float* __restrict__ out, int Bn) {
  __shared__ float sl[4], sc[4];
  float loss = 0.f, cnt = 0.f;
  for (int i = threadIdx.x; i < Bn; i += 256) {
    float p = psum[i], n = nsum[i];
    if (p > 0.f && n > 0.f) {
      loss += 0.5f * log1pf(p) + 0.02f * log1pf(n);
      cnt += 1.f;
    }
  }
#pragma unroll
  for (int m = 1; m < 64; m <<= 1) {
    loss += __shfl_xor(loss, m);
    cnt  += __shfl_xor(cnt, m);
  }
  int wave = threadIdx.x >> 6, lane = threadIdx.x & 63;
  if (lane == 0) { sl[wave] = loss; sc[wave] = cnt; }
  __syncthreads();
  if (threadIdx.x == 0) {
    float L = sl[0] + sl[1] + sl[2] + sl[3];
    float C = sc[0] + sc[1] + sc[2] + sc[3];
    out[0] = L / (float)Bn;
    out[1] = 1.0f - C / (float)Bn;
  }
}

extern "C" void kernel_launch(void* const* d_in, const int* in_sizes, int n_in,
                              void* d_out, int out_size, void* d_ws, size_t ws_size,
                              hipStream_t stream) {
  const float* feats  = (const float*)d_in[0];
  const int*   labels = (const int*)d_in[1];
  const int Bn = in_sizes[1];          // 8192
  float* out = (float*)d_out;

  unsigned* minord = (unsigned*)d_ws;
  unsigned* maxord = minord + Bn;
  float*    psum   = (float*)(maxord + Bn);
  float*    nsum   = psum + Bn;
  unsigned short* fb = (unsigned short*)(nsum + Bn);   // bf16 feats, 4MB

  init_kernel<<<(Bn + 255) / 256, 256, 0, stream>>>(minord, maxord, psum, nsum, Bn);

  int n4 = Bn * D / 4;
  convert_kernel<<<(n4 + 255) / 256, 256, 0, stream>>>(feats, fb, n4);

  dim3 grid(Bn / BM, Bn / (BN * CTILES));   // 64 x 8 = 512 blocks
  pair_kernel<1><<<grid, 256, 0, stream>>>(fb, labels, minord, maxord, psum, nsum);
  pair_kernel<2><<<grid, 256, 0, stream>>>(fb, labels, minord, maxord, psum, nsum);
  finalize_kernel<<<1, 256, 0, stream>>>(psum, nsum, out, Bn);
}